// Round 16
// baseline (1235.906 us; speedup 1.0000x reference)
//
#include <hip/hip_runtime.h>

#define BB 8
#define NPTS 2048
#define DD 256
#define CCH 128
#define NCLASS 50
#define LOG2E 1.4426950408889634f

typedef __attribute__((ext_vector_type(8))) short short8;
typedef __attribute__((ext_vector_type(4))) float f32x4;
typedef unsigned short u16;
#define MFMA16(a,b,c) __builtin_amdgcn_mfma_f32_16x16x32_bf16(a,b,c,0,0,0)

__device__ __forceinline__ u16 f2bf(float x){
  union { float f; unsigned int u; } v; v.f = x;
  unsigned int r = v.u + 0x7FFFu + ((v.u >> 16) & 1u);
  return (u16)(r >> 16);
}
__device__ __forceinline__ float bf2f(u16 u){
  union { unsigned int u32; float f; } v; v.u32 = ((unsigned int)u) << 16; return v.f;
}
__device__ __forceinline__ void split2(float x, u16& h, u16& l){
  h = f2bf(x); l = f2bf(x - bf2f(h));
}
__device__ __forceinline__ short8 ld8(const u16* p){ return *(const short8*)p; }
__device__ __forceinline__ short8 zero8(){ short8 z = {0,0,0,0,0,0,0,0}; return z; }

// ---------- weight pre-split ----------
struct WSplit {
  const float* src[12];
  int cnt[12];
  int off[12];
};
__global__ __launch_bounds__(256) void wsplit_kernel(WSplit wsp, u16* __restrict__ H,
                                                     u16* __restrict__ L)
{
  int seg = blockIdx.y;
  int idx = blockIdx.x*256 + threadIdx.x;
  if (idx >= wsp.cnt[seg]) return;
  float v = wsp.src[seg][idx];
  u16 h, l; split2(v, h, l);
  H[wsp.off[seg]+idx] = h; L[wsp.off[seg]+idx] = l;
}

// ---------- ek1: eA^T, eB^T split bf16 [b][d][n] ----------
__global__ __launch_bounds__(256) void ek1_kernel(
    const float* __restrict__ xyz, const float* __restrict__ A, const float* __restrict__ Bm,
    u16* __restrict__ ATrh, u16* __restrict__ ATrl, u16* __restrict__ ATih, u16* __restrict__ ATil,
    u16* __restrict__ BTrh, u16* __restrict__ BTrl, u16* __restrict__ BTih, u16* __restrict__ BTil)
{
  size_t idx = (size_t)blockIdx.x*256 + threadIdx.x;
  int n = (int)(idx & (NPTS-1));
  int d = (int)((idx >> 11) & (DD-1));
  int b = (int)(idx >> 19);
  float p0 = xyz[((size_t)b*3+0)*NPTS+n];
  float p1 = xyz[((size_t)b*3+1)*NPTS+n];
  float p2 = xyz[((size_t)b*3+2)*NPTS+n];
  float phA = p0*A[d] + p1*A[DD+d] + p2*A[2*DD+d];
  float phB = p0*Bm[d] + p1*Bm[DD+d] + p2*Bm[2*DD+d];
  float sa, ca, sb, cb;
  sincosf(phA, &sa, &ca);
  sincosf(phB, &sb, &cb);
  size_t off = ((size_t)b*DD + d)*NPTS + n;
  u16 h, l;
  split2(ca, h, l); ATrh[off] = h; ATrl[off] = l;
  split2(sa, h, l); ATih[off] = h; ATil[off] = l;
  split2(cb, h, l); BTrh[off] = h; BTrl[off] = l;
  split2(sb, h, l); BTih[off] = h; BTil[off] = l;
}

// ---------- ek2: eB split bf16 [b][n][d] ----------
__global__ __launch_bounds__(256) void ek2_kernel(
    const float* __restrict__ xyz, const float* __restrict__ Bm,
    u16* __restrict__ Brh, u16* __restrict__ Brl, u16* __restrict__ Bih, u16* __restrict__ Bil)
{
  size_t idx = (size_t)blockIdx.x*256 + threadIdx.x;
  int d = (int)(idx & (DD-1));
  int n = (int)((idx >> 8) & (NPTS-1));
  int b = (int)(idx >> 19);
  float p0 = xyz[((size_t)b*3+0)*NPTS+n];
  float p1 = xyz[((size_t)b*3+1)*NPTS+n];
  float p2 = xyz[((size_t)b*3+2)*NPTS+n];
  float phB = p0*Bm[d] + p1*Bm[DD+d] + p2*Bm[2*DD+d];
  float sb, cb;
  sincosf(phB, &sb, &cb);
  size_t off = ((size_t)b*NPTS + n)*DD + d;
  u16 h, l;
  split2(cb, h, l); Brh[off] = h; Brl[off] = l;
  split2(sb, h, l); Bih[off] = h; Bil[off] = l;
}

// ---------- inner partial (split-K x4) ----------
__global__ __launch_bounds__(256) void inner_mfma_kernel(
    const u16* __restrict__ ATrh, const u16* __restrict__ ATrl,
    const u16* __restrict__ ATih, const u16* __restrict__ ATil,
    const u16* __restrict__ BTrh, const u16* __restrict__ BTrl,
    const u16* __restrict__ BTih, const u16* __restrict__ BTil,
    float2* __restrict__ PART)
{
  int z = blockIdx.z; int b = z & 7; int ch = z >> 3;
  int e0 = blockIdx.y*64, d0 = blockIdx.x*64;
  int tid = threadIdx.x, lane = tid & 63, w = tid >> 6;
  int wr = (w >> 1)*32, wc = (w & 1)*32;
  int r16 = lane & 15, g4 = lane >> 4;
  f32x4 re[2][2] = {}, ip[2][2] = {}, iq[2][2] = {};
  size_t ar_[2], br_[2];
  #pragma unroll
  for (int rg = 0; rg < 2; rg++) {
    ar_[rg] = ((size_t)b*DD + (e0 + wr + rg*16 + r16))*NPTS + g4*8;
    br_[rg] = ((size_t)b*DD + (d0 + wc + rg*16 + r16))*NPTS + g4*8;
  }
  int kbeg = ch*512;
  #pragma unroll 2
  for (int kk = 0; kk < 512; kk += 32) {
    int k0 = kbeg + kk;
    short8 arh[2], arl[2], aih[2], ail[2], brh[2], brl[2], bih[2], bil[2];
    #pragma unroll
    for (int rg = 0; rg < 2; rg++) {
      arh[rg] = ld8(ATrh + ar_[rg] + k0); arl[rg] = ld8(ATrl + ar_[rg] + k0);
      aih[rg] = ld8(ATih + ar_[rg] + k0); ail[rg] = ld8(ATil + ar_[rg] + k0);
      brh[rg] = ld8(BTrh + br_[rg] + k0); brl[rg] = ld8(BTrl + br_[rg] + k0);
      bih[rg] = ld8(BTih + br_[rg] + k0); bil[rg] = ld8(BTil + br_[rg] + k0);
    }
    #pragma unroll
    for (int ra = 0; ra < 2; ra++)
      #pragma unroll
      for (int rb = 0; rb < 2; rb++) {
        re[ra][rb] = MFMA16(arh[ra], brh[rb], re[ra][rb]);
        re[ra][rb] = MFMA16(arh[ra], brl[rb], re[ra][rb]);
        re[ra][rb] = MFMA16(arl[ra], brh[rb], re[ra][rb]);
        re[ra][rb] = MFMA16(aih[ra], bih[rb], re[ra][rb]);
        re[ra][rb] = MFMA16(aih[ra], bil[rb], re[ra][rb]);
        re[ra][rb] = MFMA16(ail[ra], bih[rb], re[ra][rb]);
        ip[ra][rb] = MFMA16(aih[ra], brh[rb], ip[ra][rb]);
        ip[ra][rb] = MFMA16(aih[ra], brl[rb], ip[ra][rb]);
        ip[ra][rb] = MFMA16(ail[ra], brh[rb], ip[ra][rb]);
        iq[ra][rb] = MFMA16(arh[ra], bih[rb], iq[ra][rb]);
        iq[ra][rb] = MFMA16(arh[ra], bil[rb], iq[ra][rb]);
        iq[ra][rb] = MFMA16(arl[ra], bih[rb], iq[ra][rb]);
      }
  }
  float2* outp = PART + ((size_t)(ch*BB + b)*DD)*DD;
  #pragma unroll
  for (int ra = 0; ra < 2; ra++)
    #pragma unroll
    for (int rb = 0; rb < 2; rb++)
      #pragma unroll
      for (int j = 0; j < 4; j++) {
        int e = e0 + wr + ra*16 + g4*4 + j;
        int d = d0 + wc + rb*16 + r16;
        outp[(size_t)e*DD + d] = make_float2(re[ra][rb][j], ip[ra][rb][j] - iq[ra][rb][j]);
      }
}

// ---------- reduce 4 partials -> split-bf16 innT planes ----------
__global__ __launch_bounds__(256) void innred_kernel(const float2* __restrict__ P,
    u16* __restrict__ Irh, u16* __restrict__ Irl, u16* __restrict__ Iih, u16* __restrict__ Iil)
{
  size_t i = (size_t)blockIdx.x*256 + threadIdx.x;
  const size_t S = (size_t)BB*DD*DD;
  float2 a = P[i], b = P[i+S], c = P[i+2*S], d = P[i+3*S];
  float rr = a.x+b.x+c.x+d.x, ii = a.y+b.y+c.y+d.y;
  u16 h, l;
  split2(rr, h, l); Irh[i] = h; Irl[i] = l;
  split2(ii, h, l); Iih[i] = h; Iil[i] = l;
}

// ---------- G[n][e] = sum_d eB[n,d]*inner[d,e] ----------
__global__ __launch_bounds__(256) void g_mfma_kernel(
    const u16* __restrict__ Brh, const u16* __restrict__ Brl,
    const u16* __restrict__ Bih, const u16* __restrict__ Bil,
    const u16* __restrict__ Irh, const u16* __restrict__ Irl,
    const u16* __restrict__ Iih, const u16* __restrict__ Iil,
    float2* __restrict__ G)
{
  int b = blockIdx.z;
  int n0 = blockIdx.y*64, e0 = blockIdx.x*64;
  int tid = threadIdx.x, lane = tid & 63, w = tid >> 6;
  int wr = (w >> 1)*32, wc = (w & 1)*32;
  int r16 = lane & 15, g4 = lane >> 4;
  f32x4 p[2][2] = {}, q[2][2] = {}, im[2][2] = {};
  size_t ar_[2], br_[2];
  #pragma unroll
  for (int rg = 0; rg < 2; rg++) {
    ar_[rg] = ((size_t)b*NPTS + (n0 + wr + rg*16 + r16))*DD + g4*8;
    br_[rg] = ((size_t)b*DD + (e0 + wc + rg*16 + r16))*DD + g4*8;
  }
  #pragma unroll
  for (int k0 = 0; k0 < DD; k0 += 32) {
    short8 arh[2], arl[2], aih[2], ail[2], brh[2], brl[2], bih[2], bil[2];
    #pragma unroll
    for (int rg = 0; rg < 2; rg++) {
      arh[rg] = ld8(Brh + ar_[rg] + k0); arl[rg] = ld8(Brl + ar_[rg] + k0);
      aih[rg] = ld8(Bih + ar_[rg] + k0); ail[rg] = ld8(Bil + ar_[rg] + k0);
      brh[rg] = ld8(Irh + br_[rg] + k0); brl[rg] = ld8(Irl + br_[rg] + k0);
      bih[rg] = ld8(Iih + br_[rg] + k0); bil[rg] = ld8(Iil + br_[rg] + k0);
    }
    #pragma unroll
    for (int ra = 0; ra < 2; ra++)
      #pragma unroll
      for (int rb = 0; rb < 2; rb++) {
        p[ra][rb] = MFMA16(arh[ra], brh[rb], p[ra][rb]);
        p[ra][rb] = MFMA16(arh[ra], brl[rb], p[ra][rb]);
        p[ra][rb] = MFMA16(arl[ra], brh[rb], p[ra][rb]);
        q[ra][rb] = MFMA16(aih[ra], bih[rb], q[ra][rb]);
        q[ra][rb] = MFMA16(aih[ra], bil[rb], q[ra][rb]);
        q[ra][rb] = MFMA16(ail[ra], bih[rb], q[ra][rb]);
        im[ra][rb] = MFMA16(arh[ra], bih[rb], im[ra][rb]);
        im[ra][rb] = MFMA16(arh[ra], bil[rb], im[ra][rb]);
        im[ra][rb] = MFMA16(arl[ra], bih[rb], im[ra][rb]);
        im[ra][rb] = MFMA16(aih[ra], brh[rb], im[ra][rb]);
        im[ra][rb] = MFMA16(aih[ra], brl[rb], im[ra][rb]);
        im[ra][rb] = MFMA16(ail[ra], brh[rb], im[ra][rb]);
      }
  }
  #pragma unroll
  for (int ra = 0; ra < 2; ra++)
    #pragma unroll
    for (int rb = 0; rb < 2; rb++)
      #pragma unroll
      for (int j = 0; j < 4; j++) {
        int n = n0 + wr + ra*16 + g4*4 + j;
        int e = e0 + wc + rb*16 + r16;
        G[((size_t)b*NPTS + n)*DD + e] = make_float2(p[ra][rb][j] - q[ra][rb][j], im[ra][rb][j]);
      }
}

// ---------- gnorm + split ----------
__global__ __launch_bounds__(256) void gnormsplit_kernel(const float2* __restrict__ Gf,
    u16* __restrict__ Grh, u16* __restrict__ Grl, u16* __restrict__ Gih, u16* __restrict__ Gil)
{
  size_t row = blockIdx.x;
  const float2* p = Gf + row*DD;
  int tid = threadIdx.x;
  float2 v = p[tid];
  __shared__ float red[256];
  red[tid] = v.x*v.x + v.y*v.y;
  __syncthreads();
  for (int w = 128; w > 0; w >>= 1) { if (tid < w) red[tid] += red[tid+w]; __syncthreads(); }
  float sc = 16.f * rsqrtf(red[0]);
  size_t off = row*DD + tid;
  u16 h, l;
  split2(v.x*sc, h, l); Grh[off] = h; Grl[off] = l;
  split2(v.y*sc, h, l); Gih[off] = h; Gil[off] = l;
}

// ---------- complex linear (pure split-MFMA; plain mapping) ----------
__global__ __launch_bounds__(256) void clinear_mfma_kernel(
    const u16* __restrict__ Arh, const u16* __restrict__ Arl,
    const u16* __restrict__ Aih, const u16* __restrict__ Ail,
    const u16* __restrict__ Wrh, const u16* __restrict__ Wrl,
    const u16* __restrict__ Wih, const u16* __restrict__ Wil,
    const float* __restrict__ br, const float* __restrict__ bi,
    u16* __restrict__ Orh, u16* __restrict__ Orl, u16* __restrict__ Oih, u16* __restrict__ Oil,
    const float* __restrict__ RW, float* __restrict__ GSQ, int mode)
{
  int m0 = blockIdx.y*64, o0 = blockIdx.x*64;
  int tid = threadIdx.x, lane = tid & 63, w = tid >> 6;
  int wr = (w >> 1)*32, wc = (w & 1)*32;
  int r16 = lane & 15, g4 = lane >> 4;
  f32x4 p[2][2] = {}, q[2][2] = {}, im[2][2] = {};
  size_t ar_[2], br_[2];
  #pragma unroll
  for (int rg = 0; rg < 2; rg++) {
    ar_[rg] = (size_t)(m0 + wr + rg*16 + r16)*DD + g4*8;
    br_[rg] = (size_t)(o0 + wc + rg*16 + r16)*DD + g4*8;
  }
  #pragma unroll
  for (int k0 = 0; k0 < DD; k0 += 32) {
    short8 arh[2], arl[2], aih[2], ail[2], brh[2], brl[2], bih[2], bil[2];
    #pragma unroll
    for (int rg = 0; rg < 2; rg++) {
      arh[rg] = ld8(Arh + ar_[rg] + k0); arl[rg] = ld8(Arl + ar_[rg] + k0);
      aih[rg] = ld8(Aih + ar_[rg] + k0); ail[rg] = ld8(Ail + ar_[rg] + k0);
      brh[rg] = ld8(Wrh + br_[rg] + k0); brl[rg] = ld8(Wrl + br_[rg] + k0);
      bih[rg] = ld8(Wih + br_[rg] + k0); bil[rg] = ld8(Wil + br_[rg] + k0);
    }
    #pragma unroll
    for (int ra = 0; ra < 2; ra++)
      #pragma unroll
      for (int rb = 0; rb < 2; rb++) {
        p[ra][rb] = MFMA16(arh[ra], brh[rb], p[ra][rb]);
        p[ra][rb] = MFMA16(arh[ra], brl[rb], p[ra][rb]);
        p[ra][rb] = MFMA16(arl[ra], brh[rb], p[ra][rb]);
        q[ra][rb] = MFMA16(aih[ra], bih[rb], q[ra][rb]);
        q[ra][rb] = MFMA16(aih[ra], bil[rb], q[ra][rb]);
        q[ra][rb] = MFMA16(ail[ra], bih[rb], q[ra][rb]);
        im[ra][rb] = MFMA16(arh[ra], bih[rb], im[ra][rb]);
        im[ra][rb] = MFMA16(arh[ra], bil[rb], im[ra][rb]);
        im[ra][rb] = MFMA16(arl[ra], bih[rb], im[ra][rb]);
        im[ra][rb] = MFMA16(aih[ra], brh[rb], im[ra][rb]);
        im[ra][rb] = MFMA16(aih[ra], brl[rb], im[ra][rb]);
        im[ra][rb] = MFMA16(ail[ra], brh[rb], im[ra][rb]);
      }
  }
  #pragma unroll
  for (int ra = 0; ra < 2; ra++)
    #pragma unroll
    for (int rb = 0; rb < 2; rb++) {
      int o = o0 + wc + rb*16 + r16;
      float brv = br[o], biv = bi[o];
      if (mode == 1) {
        #pragma unroll
        for (int j = 0; j < 4; j++) {
          int m = m0 + wr + ra*16 + g4*4 + j;
          float re = fmaxf(p[ra][rb][j] - q[ra][rb][j] + brv - biv, 0.f);
          float iv = fmaxf(im[ra][rb][j] + brv + biv, 0.f);
          size_t off = (size_t)m*DD + o;
          u16 h, l;
          split2(re, h, l); Orh[off] = h; Orl[off] = l;
          split2(iv, h, l); Oih[off] = h; Oil[off] = l;
        }
      } else {
        int mbase = m0 + wr + ra*16 + g4*4;
        int b = mbase >> 11, nb = mbase & (NPTS-1);
        float rwv = RW[(size_t)b*DD + o];
        float4 gv;
        #pragma unroll
        for (int j = 0; j < 4; j++) {
          float re = p[ra][rb][j] - q[ra][rb][j] + brv - biv;
          float iv = im[ra][rb][j] + brv + biv;
          ((float*)&gv)[j] = (re*re + iv*iv) * rwv;
        }
        *(float4*)(GSQ + ((size_t)b*DD + o)*NPTS + nb) = gv;
      }
    }
}

// ---------- reweight ----------
__global__ void rw_kernel(const float* __restrict__ cls, const float* __restrict__ lbl,
                          float* __restrict__ RW)
{
  int b = blockIdx.x; int d = threadIdx.x;
  float s = 0.f;
  #pragma unroll
  for (int k = 0; k < 16; k++) s += cls[b*16+k] * lbl[k*DD+d];
  RW[b*DD+d] = s;
}

// ---------- sgemm (split MFMA, pre-split W) ----------
__global__ __launch_bounds__(256) void sgemm_kernel(
    const u16* __restrict__ Wh, const u16* __restrict__ Wl,
    const float* __restrict__ X, float* __restrict__ Y,
    const float* __restrict__ RES,
    const float* __restrict__ bias, const float* __restrict__ bng, const float* __restrict__ bnb,
    u16* __restrict__ YBh, u16* __restrict__ YBl, int ybmode,
    int O, int Cin, size_t xbs, size_t ybs, size_t rbs, int flags)
{
  int b = blockIdx.z;
  int n0 = blockIdx.x*64, o0 = blockIdx.y*64;
  const float* x = X + (size_t)b*xbs;
  __shared__ u16 sXh[64][40], sXl[64][40];
  int tid = threadIdx.x, lane = tid & 63, w = tid >> 6;
  int wo = (w >> 1)*32, wn = (w & 1)*32;
  int r16 = lane & 15, g4 = lane >> 4;
  f32x4 acc[2][2] = {};
  int stc = tid >> 3;
  int stn = (tid & 7)*8;
  for (int k0 = 0; k0 < Cin; k0 += 32) {
    const float* px = x + (size_t)(k0+stc)*NPTS + n0 + stn;
    float4 u0 = *(const float4*)px;
    float4 u1 = *(const float4*)(px+4);
    float v[8] = {u0.x,u0.y,u0.z,u0.w,u1.x,u1.y,u1.z,u1.w};
    __syncthreads();
    #pragma unroll
    for (int j = 0; j < 8; j++) {
      u16 h, l; split2(v[j], h, l);
      sXh[stn+j][stc] = h; sXl[stn+j][stc] = l;
    }
    __syncthreads();
    short8 awh[2], awl[2], bxh[2], bxl[2];
    #pragma unroll
    for (int rg = 0; rg < 2; rg++) {
      int orow = o0 + wo + rg*16 + r16;
      if (orow < O) {
        size_t woff = (size_t)orow*Cin + k0 + g4*8;
        awh[rg] = ld8(Wh + woff); awl[rg] = ld8(Wl + woff);
      } else { awh[rg] = zero8(); awl[rg] = zero8(); }
      bxh[rg] = ld8(&sXh[wn + rg*16 + r16][g4*8]);
      bxl[rg] = ld8(&sXl[wn + rg*16 + r16][g4*8]);
    }
    #pragma unroll
    for (int ra = 0; ra < 2; ra++)
      #pragma unroll
      for (int rb = 0; rb < 2; rb++) {
        acc[ra][rb] = MFMA16(awh[ra], bxh[rb], acc[ra][rb]);
        acc[ra][rb] = MFMA16(awh[ra], bxl[rb], acc[ra][rb]);
        acc[ra][rb] = MFMA16(awl[ra], bxh[rb], acc[ra][rb]);
      }
  }
  #pragma unroll
  for (int ra = 0; ra < 2; ra++)
    #pragma unroll
    for (int rb = 0; rb < 2; rb++)
      #pragma unroll
      for (int j = 0; j < 4; j++) {
        int o = o0 + wo + ra*16 + g4*4 + j;
        if (o >= O) continue;
        int n = n0 + wn + rb*16 + r16;
        float v = acc[ra][rb][j];
        if (flags & 1) v += bias[o];
        if (flags & 2) v = v * (bng[o] * rsqrtf(1.f + 1e-5f)) + bnb[o];
        if (flags & 4) v = fmaxf(v, 0.f);
        if (flags & 8) v += RES[(size_t)b*rbs + (size_t)o*NPTS + n];
        if (ybmode == 0) Y[(size_t)b*ybs + (size_t)o*NPTS + n] = v;
        else if (ybmode == 1) YBh[(size_t)b*ybs + (size_t)o*NPTS + n] = f2bf(v);
        else {
          u16 h, l; split2(v, h, l);
          size_t off = ((size_t)b*NPTS + n)*32 + o;
          YBh[off] = h; YBl[off] = l;
        }
      }
}

// ---------- sastat: flash pass 1, m-chunked; XCD-pinned ----------
__global__ __launch_bounds__(256) void sastat_kernel(
    const u16* __restrict__ Qh, const u16* __restrict__ Ql,
    float* __restrict__ PM, float* __restrict__ PS)
{
  int bx = blockIdx.x;
  int b = bx & 7;
  int t = bx >> 3;
  int ch = t & 3;
  int n0 = (t >> 2)*64;
  size_t base = (size_t)b*NPTS*32;
  int tid = threadIdx.x, lane = tid & 63, wid = tid >> 6;
  int r16 = lane & 15, g4 = lane >> 4;
  size_t ao = base + (size_t)(n0 + wid*16 + r16)*32 + g4*8;
  short8 ah = ld8(Qh + ao), al = ld8(Ql + ao);
  float pm[4] = {-3.4e38f,-3.4e38f,-3.4e38f,-3.4e38f};
  float ps[4] = {0.f,0.f,0.f,0.f};
  int mbeg = ch*512, mend = mbeg + 512;
  for (int mt = mbeg; mt < mend; mt += 32) {
    size_t bo0 = base + (size_t)(mt + r16)*32 + g4*8;
    size_t bo1 = bo0 + 16*32;
    short8 bh0 = ld8(Qh+bo0), bl0 = ld8(Ql+bo0);
    short8 bh1 = ld8(Qh+bo1), bl1 = ld8(Ql+bo1);
    f32x4 a0 = {}, a1 = {};
    a0 = MFMA16(ah, bh0, a0); a0 = MFMA16(ah, bl0, a0); a0 = MFMA16(al, bh0, a0);
    a1 = MFMA16(ah, bh1, a1); a1 = MFMA16(ah, bl1, a1); a1 = MFMA16(al, bh1, a1);
    #pragma unroll
    for (int j = 0; j < 4; j++) {
      float v = fmaxf(a0[j], a1[j]);
      float mn = fmaxf(pm[j], v);
      ps[j] = ps[j]*exp2f((pm[j]-mn)*LOG2E)
            + exp2f((a0[j]-mn)*LOG2E) + exp2f((a1[j]-mn)*LOG2E);
      pm[j] = mn;
    }
  }
  #pragma unroll
  for (int j = 0; j < 4; j++) {
    float m = pm[j], s = ps[j];
    #pragma unroll
    for (int d = 1; d < 16; d <<= 1) {
      float om = __shfl_xor(m, d);
      float os = __shfl_xor(s, d);
      float mn = fmaxf(m, om);
      s = s*exp2f((m-mn)*LOG2E) + os*exp2f((om-mn)*LOG2E);
      m = mn;
    }
    if (r16 == 0) {
      int n_ = n0 + wid*16 + g4*4 + j;
      size_t off = ((size_t)ch*BB + b)*NPTS + n_;
      PM[off] = m; PS[off] = s;
    }
  }
}

// ---------- comb1: mx/rs from 4 chunk partials ----------
__global__ __launch_bounds__(256) void comb1_kernel(
    const float* __restrict__ PM, const float* __restrict__ PS,
    float* __restrict__ MX, float* __restrict__ RS)
{
  size_t i = (size_t)blockIdx.x*256 + threadIdx.x;
  const size_t S = (size_t)BB*NPTS;
  float m0 = PM[i], m1 = PM[i+S], m2 = PM[i+2*S], m3 = PM[i+3*S];
  float mx = fmaxf(fmaxf(m0,m1), fmaxf(m2,m3));
  float den = PS[i]*exp2f((m0-mx)*LOG2E) + PS[i+S]*exp2f((m1-mx)*LOG2E)
            + PS[i+2*S]*exp2f((m2-mx)*LOG2E) + PS[i+3*S]*exp2f((m3-mx)*LOG2E);
  MX[i] = mx; RS[i] = 1.f/den;
}

// ---------- fused flash pass 2 + PV: barrier-free, in-register P, c-quarter split,
// full n-loop per wave, DIRECT final write. grid 1024 flat, 256 thr.
// b = bx&7; idx = bx>>3: mtile = idx>>2 (0..31), cq = idx&3.
// Wave w: m rows [mtile*64 + w*16, +16), channels [cq*32, +32), all n.
__global__ __launch_bounds__(256) void fused_pv_kernel(
    const u16* __restrict__ Qh, const u16* __restrict__ Ql,
    const float* __restrict__ MX, const float* __restrict__ RS,
    const u16* __restrict__ XV, const float* __restrict__ XRES, size_t res_bs,
    float* __restrict__ OUT)
{
  int bx = blockIdx.x;
  int b = bx & 7;
  int idx = bx >> 3;
  int mtile = idx >> 2;
  int cq = idx & 3;
  int tid = threadIdx.x, lane = tid & 63, w = tid >> 6;
  int r16 = lane & 15, g4 = lane >> 4;
  int m0w = mtile*64 + w*16;
  int cw = cq*32;
  size_t qbase = (size_t)b*NPTS*32;
  const u16* xv = XV + (size_t)b*CCH*NPTS;
  const float* mx = MX + (size_t)b*NPTS;
  const float* rs = RS + (size_t)b*NPTS;
  size_t mo = qbase + (size_t)(m0w + r16)*32 + g4*8;
  short8 mbh = ld8(Qh + mo), mbl = ld8(Ql + mo);
  const u16* pb0 = xv + (size_t)(cw + r16)*NPTS + g4*8;
  const u16* pb1 = pb0 + (size_t)16*NPTS;
  f32x4 acc[2] = {};
  float csl = 0.f;
  int sq = (g4 & 1)*32 + r16;
  size_t qn0 = qbase + (size_t)r16*32 + g4*8;
  // prefetch iter 0
  short8 nh0 = ld8(Qh + qn0), nl0 = ld8(Ql + qn0);
  short8 nh1 = ld8(Qh + qn0 + 16*32), nl1 = ld8(Ql + qn0 + 16*32);
  short8 bf0 = ld8(pb0), bf1 = ld8(pb1);
  for (int nt = 0; nt < NPTS; nt += 32) {
    short8 xnh0 = nh0, xnl0 = nl0, xnh1 = nh1, xnl1 = nl1;
    short8 xbf0 = bf0, xbf1 = bf1;
    if (nt + 32 < NPTS) {
      size_t o = qn0 + (size_t)(nt + 32)*32;
      nh0 = ld8(Qh + o); nl0 = ld8(Ql + o);
      nh1 = ld8(Qh + o + 16*32); nl1 = ld8(Ql + o + 16*32);
      bf0 = ld8(pb0 + nt + 32); bf1 = ld8(pb1 + nt + 32);
    }
    f32x4 e0 = {}, e1 = {};
    e0 = MFMA16(xnh0, mbh, e0); e0 = MFMA16(xnh0, mbl, e0); e0 = MFMA16(xnl0, mbh, e0);
    e1 = MFMA16(xnh1, mbh, e1); e1 = MFMA16(xnh1, mbl, e1); e1 = MFMA16(xnl1, mbh, e1);
    unsigned pk00, pk01, pk10, pk11;
    {
      float4 m4 = *(const float4*)&mx[nt + 4*g4];
      float4 r4 = *(const float4*)&rs[nt + 4*g4];
      float t0 = exp2f((e0[0]-m4.x)*LOG2E)*r4.x;
      float t1 = exp2f((e0[1]-m4.y)*LOG2E)*r4.y;
      float t2 = exp2f((e0[2]-m4.z)*LOG2E)*r4.z;
      float t3 = exp2f((e0[3]-m4.w)*LOG2E)*r4.w;
      csl += t0+t1+t2+t3;
      pk00 = (unsigned)f2bf(t0) | ((unsigned)f2bf(t1)<<16);
      pk01 = (unsigned)f2bf(t2) | ((unsigned)f2bf(t3)<<16);
      m4 = *(const float4*)&mx[nt + 16 + 4*g4];
      r4 = *(const float4*)&rs[nt + 16 + 4*g4];
      t0 = exp2f((e1[0]-m4.x)*LOG2E)*r4.x;
      t1 = exp2f((e1[1]-m4.y)*LOG2E)*r4.y;
      t2 = exp2f((e1[2]-m4.z)*LOG2E)*r4.z;
      t3 = exp2f((e1[3]-m4.w)*LOG2E)*r4.w;
      csl += t0+t1+t2+t3;
      pk10 = (unsigned)f2bf(t0) | ((unsigned)f2bf(t1)<<16);
      pk11 = (unsigned)f2bf(t2) | ((unsigned)f2bf(t3)<<16);
    }
    int a00 = __shfl((int)pk00, sq);
    int a01 = __shfl((int)pk01, sq);
    int a10 = __shfl((int)pk10, sq);
    int a11 = __shfl((int)pk11, sq);
    int b00 = __shfl((int)pk00, sq+16);
    int b01 = __shfl((int)pk01, sq+16);
    int b10 = __shfl((int)pk10, sq+16);
    int b11 = __shfl((int)pk11, sq+16);
    bool lo = (lane < 32);
    union { int u[4]; short8 s; } af;
    af.u[0] = lo ? a00 : a10;
    af.u[1] = lo ? a01 : a11;
    af.u[2] = lo ? b00 : b10;
    af.u[3] = lo ? b01 : b11;
    acc[0] = MFMA16(af.s, xbf0, acc[0]);
    acc[1] = MFMA16(af.s, xbf1, acc[1]);
  }
  // csum for wave's 16 m (complete over all n)
  csl += __shfl_xor(csl, 16);
  csl += __shfl_xor(csl, 32);
  float ci[4];
  #pragma unroll
  for (int j = 0; j < 4; j++) ci[j] = 1.f/(1e-9f + __shfl(csl, 4*g4 + j));
  #pragma unroll
  for (int ct = 0; ct < 2; ct++) {
    int c = cw + ct*16 + r16;
    #pragma unroll
    for (int j = 0; j < 4; j++) {
      int m = m0w + 4*g4 + j;
      OUT[((size_t)b*CCH + c)*NPTS + m] =
          XRES[(size_t)b*res_bs + (size_t)c*NPTS + m] - acc[ct][j]*ci[j];
    }
  }
}

// ---------- log_softmax + transpose ----------
__global__ __launch_bounds__(256) void lsm_kernel(const float* __restrict__ Y,
                                                  float* __restrict__ OUT)
{
  int idx = blockIdx.x*256 + threadIdx.x;
  int b = idx >> 11, n = idx & (NPTS-1);
  const float* p = Y + (size_t)b*NCLASS*NPTS + n;
  float m = -3.4e38f;
  #pragma unroll
  for (int k = 0; k < NCLASS; k++) m = fmaxf(m, p[(size_t)k*NPTS]);
  float s = 0.f;
  #pragma unroll
  for (int k = 0; k < NCLASS; k++) s += expf(p[(size_t)k*NPTS] - m);
  float L = m + logf(s);
  float* o = OUT + (size_t)idx*NCLASS;
  #pragma unroll
  for (int k = 0; k < NCLASS; k++) o[k] = p[(size_t)k*NPTS] - L;
}

extern "C" void kernel_launch(void* const* d_in, const int* in_sizes, int n_in,
                              void* d_out, int out_size, void* d_ws, size_t ws_size,
                              hipStream_t stream)
{
  (void)in_sizes; (void)n_in; (void)out_size; (void)ws_size;
  const float* xyz  = (const float*)d_in[0];
  const float* cls  = (const float*)d_in[1];
  const float* Amat = (const float*)d_in[2];
  const float* Bm   = (const float*)d_in[3];
  const float* W1r  = (const float*)d_in[4];
  const float* b1r  = (const float*)d_in[5];
  const float* W1i  = (const float*)d_in[6];
  const float* b1i  = (const float*)d_in[7];
  const float* W2r  = (const float*)d_in[8];
  const float* b2r  = (const float*)d_in[9];
  const float* W2i  = (const float*)d_in[10];
  const float* b2i  = (const float*)d_in[11];
  const float* lbl  = (const float*)d_in[12];
  const float* ftw1 = (const float*)d_in[13];
  const float* ftg1 = (const float*)d_in[14];
  const float* ftb1 = (const float*)d_in[15];
  const float* ftw2 = (const float*)d_in[16];
  const float* ftg2 = (const float*)d_in[17];
  const float* ftb2 = (const float*)d_in[18];
  const float* saqk = (const float*)d_in[19];
  const float* savw = (const float*)d_in[20];
  const float* savb = (const float*)d_in[21];
  const float* satw = (const float*)d_in[22];
  const float* satb = (const float*)d_in[23];
  const float* sag  = (const float*)d_in[24];
  const float* sab  = (const float*)d_in[25];
  const float* fusew= (const float*)d_in[26];
  const float* fuseg= (const float*)d_in[27];
  const float* fuseb= (const float*)d_in[28];
  const float* c1w  = (const float*)d_in[29];
  const float* c1b  = (const float*)d_in[30];
  const float* bn1g = (const float*)d_in[31];
  const float* bn1b = (const float*)d_in[32];
  const float* c2w  = (const float*)d_in[33];
  const float* c2b  = (const float*)d_in[34];
  float* out = (float*)d_out;

  float* ws = (float*)d_ws;
  const size_t PS  = (size_t)BB*DD*NPTS;
  const size_t ISZ = (size_t)BB*DD*DD;
  u16* U = (u16*)ws;
  u16 *ATrh = U+0*PS, *ATrl = U+1*PS, *ATih = U+2*PS, *ATil = U+3*PS;
  u16 *BTrh = U+4*PS, *BTrl = U+5*PS, *BTih = U+6*PS, *BTil = U+7*PS;
  u16 *Bnrh = U+8*PS, *Bnrl = U+9*PS, *Bnih = U+10*PS, *Bnil = U+11*PS;
  u16 *Irh = U+12*PS, *Irl = U+12*PS+ISZ, *Iih = U+12*PS+2*ISZ, *Iil = U+12*PS+3*ISZ;
  float* gsq = (float*)(U + 12*PS + 4*ISZ);
  float2* PART = (float2*)gsq;
  float2* Gf = (float2*)ws;
  u16 *G1rh = U+4*PS, *G1rl = U+5*PS, *G1ih = U+6*PS, *G1il = U+7*PS;
  u16 *G2rh = U+8*PS, *G2rl = U+9*PS, *G2ih = U+10*PS, *G2il = U+11*PS;
  size_t p = (size_t)BB*NPTS*NPTS;
  float* xfeat = ws + p;  p += (size_t)BB*CCH*NPTS;
  float* feats = ws + p;  p += (size_t)BB*4*CCH*NPTS;
  float* xt1   = ws + p;  p += (size_t)BB*CCH*NPTS;
  float* xt2   = ws + p;  p += (size_t)BB*CCH*NPTS;
  float* ybuf  = ws + p;  p += (size_t)BB*NCLASS*NPTS;
  float* rwb   = ws + p;  p += (size_t)BB*DD;
  float* mxv   = ws + p;  p += (size_t)BB*NPTS;
  float* rsv   = ws + p;  p += (size_t)BB*NPTS;
  float* PMb   = ws + p;  p += (size_t)4*BB*NPTS;
  float* PSb   = ws + p;  p += (size_t)4*BB*NPTS;
  u16* xqh = (u16*)(ws + p);
  u16* xql = xqh + (size_t)BB*NPTS*32;
  u16* xvb = xql + (size_t)BB*NPTS*32;
  u16* wpH = xvb + (size_t)BB*CCH*NPTS;
  u16* wpL = wpH + 557056;

  const int o_w1r=0, o_w1i=65536, o_w2r=131072, o_w2i=196608, o_ft1=262144,
            o_ft2=294912, o_qk=311296, o_vw=327680, o_tw=393216, o_fu=458752,
            o_c1=524288, o_c2=540672;
  WSplit wsp;
  const float* srcs[12] = {W1r,W1i,W2r,W2i,ftw1,ftw2,saqk,savw,satw,fusew,c1w,c2w};
  const int cnts[12] = {65536,65536,65536,65536,32768,16384,16384,65536,65536,65536,16384,6400};
  const int offs[12] = {o_w1r,o_w1i,o_w2r,o_w2i,o_ft1,o_ft2,o_qk,o_vw,o_tw,o_fu,o_c1,o_c2};
  for (int i = 0; i < 12; i++) { wsp.src[i]=srcs[i]; wsp.cnt[i]=cnts[i]; wsp.off[i]=offs[i]; }

  wsplit_kernel<<<dim3(256, 12), 256, 0, stream>>>(wsp, wpH, wpL);
  rw_kernel<<<BB, DD, 0, stream>>>(cls, lbl, rwb);
  ek1_kernel<<<(int)(PS/256), 256, 0, stream>>>(xyz, Amat, Bm,
      ATrh, ATrl, ATih, ATil, BTrh, BTrl, BTih, BTil);
  ek2_kernel<<<(int)(PS/256), 256, 0, stream>>>(xyz, Bm, Bnrh, Bnrl, Bnih, Bnil);
  inner_mfma_kernel<<<dim3(DD/64, DD/64, BB*4), 256, 0, stream>>>(
      ATrh, ATrl, ATih, ATil, BTrh, BTrl, BTih, BTil, PART);
  innred_kernel<<<(int)(ISZ/256), 256, 0, stream>>>(PART, Irh, Irl, Iih, Iil);
  g_mfma_kernel<<<dim3(DD/64, NPTS/64, BB), 256, 0, stream>>>(
      Bnrh, Bnrl, Bnih, Bnil, Irh, Irl, Iih, Iil, Gf);
  gnormsplit_kernel<<<BB*NPTS, 256, 0, stream>>>(Gf, G1rh, G1rl, G1ih, G1il);
  clinear_mfma_kernel<<<dim3(DD/64, (BB*NPTS)/64), 256, 0, stream>>>(
      G1rh, G1rl, G1ih, G1il, wpH+o_w1r, wpL+o_w1r, wpH+o_w1i, wpL+o_w1i,
      b1r, b1i, G2rh, G2rl, G2ih, G2il, nullptr, nullptr, 1);
  clinear_mfma_kernel<<<dim3(DD/64, (BB*NPTS)/64), 256, 0, stream>>>(
      G2rh, G2rl, G2ih, G2il, wpH+o_w2r, wpL+o_w2r, wpH+o_w2i, wpL+o_w2i,
      b2r, b2i, nullptr, nullptr, nullptr, nullptr, rwb, gsq, 2);

  sgemm_kernel<<<dim3(NPTS/64, CCH/64, BB), 256, 0, stream>>>(
      wpH+o_ft1, wpL+o_ft1, gsq, xt1, nullptr, nullptr, ftg1, ftb1, nullptr, nullptr, 0,
      CCH, DD, (size_t)DD*NPTS, (size_t)CCH*NPTS, 0, 2|4);
  sgemm_kernel<<<dim3(NPTS/64, CCH/64, BB), 256, 0, stream>>>(
      wpH+o_ft2, wpL+o_ft2, xt1, xfeat, nullptr, nullptr, ftg2, ftb2, nullptr, nullptr, 0,
      CCH, CCH, (size_t)CCH*NPTS, (size_t)CCH*NPTS, 0, 2);

  const float* xsrc = xfeat;
  size_t xbs = (size_t)CCH*NPTS;
  for (int i = 0; i < 4; i++) {
    sgemm_kernel<<<dim3(NPTS/64, 1, BB), 256, 0, stream>>>(
        wpH+o_qk + i*32*CCH, wpL+o_qk + i*32*CCH, xsrc, nullptr, nullptr,
        nullptr, nullptr, nullptr, xqh, xql, 2, 32, CCH, xbs, 0, 0, 0);
    sastat_kernel<<<1024, 256, 0, stream>>>(xqh, xql, PMb, PSb);
    comb1_kernel<<<(BB*NPTS)/256, 256, 0, stream>>>(PMb, PSb, mxv, rsv);
    sgemm_kernel<<<dim3(NPTS/64, CCH/64, BB), 256, 0, stream>>>(
        wpH+o_vw + i*CCH*CCH, wpL+o_vw + i*CCH*CCH, xsrc, nullptr, nullptr,
        savb + i*CCH, nullptr, nullptr, xvb, nullptr, 1, CCH, CCH, xbs,
        (size_t)CCH*NPTS, 0, 1);
    fused_pv_kernel<<<1024, 256, 0, stream>>>(
        xqh, xql, mxv, rsv, xvb, xsrc, xbs, xt2);
    sgemm_kernel<<<dim3(NPTS/64, CCH/64, BB), 256, 0, stream>>>(
        wpH+o_tw + i*CCH*CCH, wpL+o_tw + i*CCH*CCH, xt2, feats + (size_t)i*CCH*NPTS, xsrc,
        satb + i*CCH, sag + i*CCH, sab + i*CCH, nullptr, nullptr, 0,
        CCH, CCH, (size_t)CCH*NPTS, (size_t)4*CCH*NPTS, xbs, 1|2|4|8);
    xsrc = feats + (size_t)i*CCH*NPTS;
    xbs = (size_t)4*CCH*NPTS;
  }

  sgemm_kernel<<<dim3(NPTS/64, CCH/64, BB), 256, 0, stream>>>(
      wpH+o_fu, wpL+o_fu, feats, xt1, nullptr, nullptr, fuseg, fuseb, nullptr, nullptr, 0,
      CCH, 4*CCH, (size_t)4*CCH*NPTS, (size_t)CCH*NPTS, 0, 2|4);
  sgemm_kernel<<<dim3(NPTS/64, CCH/64, BB), 256, 0, stream>>>(
      wpH+o_c1, wpL+o_c1, xt1, xt2, nullptr, c1b, bn1g, bn1b, nullptr, nullptr, 0,
      CCH, CCH, (size_t)CCH*NPTS, (size_t)CCH*NPTS, 0, 1|2|4);
  sgemm_kernel<<<dim3(NPTS/64, 1, BB), 256, 0, stream>>>(
      wpH+o_c2, wpL+o_c2, xt2, ybuf, nullptr, c2b, nullptr, nullptr, nullptr, nullptr, 0,
      NCLASS, CCH, (size_t)CCH*NPTS, (size_t)NCLASS*NPTS, 0, 1);
  lsm_kernel<<<(BB*NPTS)/256, 256, 0, stream>>>(ybuf, out);
}

// Round 17
// 961.732 us; speedup vs baseline: 1.2851x; 1.2851x over previous
//
#include <hip/hip_runtime.h>

#define BB 8
#define NPTS 2048
#define DD 256
#define CCH 128
#define NCLASS 50
#define LOG2E 1.4426950408889634f

typedef __attribute__((ext_vector_type(8))) short short8;
typedef __attribute__((ext_vector_type(4))) float f32x4;
typedef unsigned short u16;
#define MFMA16(a,b,c) __builtin_amdgcn_mfma_f32_16x16x32_bf16(a,b,c,0,0,0)

__device__ __forceinline__ u16 f2bf(float x){
  union { float f; unsigned int u; } v; v.f = x;
  unsigned int r = v.u + 0x7FFFu + ((v.u >> 16) & 1u);
  return (u16)(r >> 16);
}
__device__ __forceinline__ float bf2f(u16 u){
  union { unsigned int u32; float f; } v; v.u32 = ((unsigned int)u) << 16; return v.f;
}
__device__ __forceinline__ void split2(float x, u16& h, u16& l){
  h = f2bf(x); l = f2bf(x - bf2f(h));
}
__device__ __forceinline__ short8 ld8(const u16* p){ return *(const short8*)p; }
__device__ __forceinline__ short8 zero8(){ short8 z = {0,0,0,0,0,0,0,0}; return z; }

// ---------- weight pre-split ----------
struct WSplit {
  const float* src[12];
  int cnt[12];
  int off[12];
};
__global__ __launch_bounds__(256) void wsplit_kernel(WSplit wsp, u16* __restrict__ H,
                                                     u16* __restrict__ L)
{
  int seg = blockIdx.y;
  int idx = blockIdx.x*256 + threadIdx.x;
  if (idx >= wsp.cnt[seg]) return;
  float v = wsp.src[seg][idx];
  u16 h, l; split2(v, h, l);
  H[wsp.off[seg]+idx] = h; L[wsp.off[seg]+idx] = l;
}

// ---------- ek1: eA^T, eB^T split bf16 [b][d][n] ----------
__global__ __launch_bounds__(256) void ek1_kernel(
    const float* __restrict__ xyz, const float* __restrict__ A, const float* __restrict__ Bm,
    u16* __restrict__ ATrh, u16* __restrict__ ATrl, u16* __restrict__ ATih, u16* __restrict__ ATil,
    u16* __restrict__ BTrh, u16* __restrict__ BTrl, u16* __restrict__ BTih, u16* __restrict__ BTil)
{
  size_t idx = (size_t)blockIdx.x*256 + threadIdx.x;
  int n = (int)(idx & (NPTS-1));
  int d = (int)((idx >> 11) & (DD-1));
  int b = (int)(idx >> 19);
  float p0 = xyz[((size_t)b*3+0)*NPTS+n];
  float p1 = xyz[((size_t)b*3+1)*NPTS+n];
  float p2 = xyz[((size_t)b*3+2)*NPTS+n];
  float phA = p0*A[d] + p1*A[DD+d] + p2*A[2*DD+d];
  float phB = p0*Bm[d] + p1*Bm[DD+d] + p2*Bm[2*DD+d];
  float sa, ca, sb, cb;
  sincosf(phA, &sa, &ca);
  sincosf(phB, &sb, &cb);
  size_t off = ((size_t)b*DD + d)*NPTS + n;
  u16 h, l;
  split2(ca, h, l); ATrh[off] = h; ATrl[off] = l;
  split2(sa, h, l); ATih[off] = h; ATil[off] = l;
  split2(cb, h, l); BTrh[off] = h; BTrl[off] = l;
  split2(sb, h, l); BTih[off] = h; BTil[off] = l;
}

// ---------- ek2: eB split bf16 [b][n][d] ----------
__global__ __launch_bounds__(256) void ek2_kernel(
    const float* __restrict__ xyz, const float* __restrict__ Bm,
    u16* __restrict__ Brh, u16* __restrict__ Brl, u16* __restrict__ Bih, u16* __restrict__ Bil)
{
  size_t idx = (size_t)blockIdx.x*256 + threadIdx.x;
  int d = (int)(idx & (DD-1));
  int n = (int)((idx >> 8) & (NPTS-1));
  int b = (int)(idx >> 19);
  float p0 = xyz[((size_t)b*3+0)*NPTS+n];
  float p1 = xyz[((size_t)b*3+1)*NPTS+n];
  float p2 = xyz[((size_t)b*3+2)*NPTS+n];
  float phB = p0*Bm[d] + p1*Bm[DD+d] + p2*Bm[2*DD+d];
  float sb, cb;
  sincosf(phB, &sb, &cb);
  size_t off = ((size_t)b*NPTS + n)*DD + d;
  u16 h, l;
  split2(cb, h, l); Brh[off] = h; Brl[off] = l;
  split2(sb, h, l); Bih[off] = h; Bil[off] = l;
}

// ---------- inner partial (split-K x4) ----------
__global__ __launch_bounds__(256) void inner_mfma_kernel(
    const u16* __restrict__ ATrh, const u16* __restrict__ ATrl,
    const u16* __restrict__ ATih, const u16* __restrict__ ATil,
    const u16* __restrict__ BTrh, const u16* __restrict__ BTrl,
    const u16* __restrict__ BTih, const u16* __restrict__ BTil,
    float2* __restrict__ PART)
{
  int z = blockIdx.z; int b = z & 7; int ch = z >> 3;
  int e0 = blockIdx.y*64, d0 = blockIdx.x*64;
  int tid = threadIdx.x, lane = tid & 63, w = tid >> 6;
  int wr = (w >> 1)*32, wc = (w & 1)*32;
  int r16 = lane & 15, g4 = lane >> 4;
  f32x4 re[2][2] = {}, ip[2][2] = {}, iq[2][2] = {};
  size_t ar_[2], br_[2];
  #pragma unroll
  for (int rg = 0; rg < 2; rg++) {
    ar_[rg] = ((size_t)b*DD + (e0 + wr + rg*16 + r16))*NPTS + g4*8;
    br_[rg] = ((size_t)b*DD + (d0 + wc + rg*16 + r16))*NPTS + g4*8;
  }
  int kbeg = ch*512;
  #pragma unroll 2
  for (int kk = 0; kk < 512; kk += 32) {
    int k0 = kbeg + kk;
    short8 arh[2], arl[2], aih[2], ail[2], brh[2], brl[2], bih[2], bil[2];
    #pragma unroll
    for (int rg = 0; rg < 2; rg++) {
      arh[rg] = ld8(ATrh + ar_[rg] + k0); arl[rg] = ld8(ATrl + ar_[rg] + k0);
      aih[rg] = ld8(ATih + ar_[rg] + k0); ail[rg] = ld8(ATil + ar_[rg] + k0);
      brh[rg] = ld8(BTrh + br_[rg] + k0); brl[rg] = ld8(BTrl + br_[rg] + k0);
      bih[rg] = ld8(BTih + br_[rg] + k0); bil[rg] = ld8(BTil + br_[rg] + k0);
    }
    #pragma unroll
    for (int ra = 0; ra < 2; ra++)
      #pragma unroll
      for (int rb = 0; rb < 2; rb++) {
        re[ra][rb] = MFMA16(arh[ra], brh[rb], re[ra][rb]);
        re[ra][rb] = MFMA16(arh[ra], brl[rb], re[ra][rb]);
        re[ra][rb] = MFMA16(arl[ra], brh[rb], re[ra][rb]);
        re[ra][rb] = MFMA16(aih[ra], bih[rb], re[ra][rb]);
        re[ra][rb] = MFMA16(aih[ra], bil[rb], re[ra][rb]);
        re[ra][rb] = MFMA16(ail[ra], bih[rb], re[ra][rb]);
        ip[ra][rb] = MFMA16(aih[ra], brh[rb], ip[ra][rb]);
        ip[ra][rb] = MFMA16(aih[ra], brl[rb], ip[ra][rb]);
        ip[ra][rb] = MFMA16(ail[ra], brh[rb], ip[ra][rb]);
        iq[ra][rb] = MFMA16(arh[ra], bih[rb], iq[ra][rb]);
        iq[ra][rb] = MFMA16(arh[ra], bil[rb], iq[ra][rb]);
        iq[ra][rb] = MFMA16(arl[ra], bih[rb], iq[ra][rb]);
      }
  }
  float2* outp = PART + ((size_t)(ch*BB + b)*DD)*DD;
  #pragma unroll
  for (int ra = 0; ra < 2; ra++)
    #pragma unroll
    for (int rb = 0; rb < 2; rb++)
      #pragma unroll
      for (int j = 0; j < 4; j++) {
        int e = e0 + wr + ra*16 + g4*4 + j;
        int d = d0 + wc + rb*16 + r16;
        outp[(size_t)e*DD + d] = make_float2(re[ra][rb][j], ip[ra][rb][j] - iq[ra][rb][j]);
      }
}

// ---------- reduce 4 partials -> split-bf16 innT planes ----------
__global__ __launch_bounds__(256) void innred_kernel(const float2* __restrict__ P,
    u16* __restrict__ Irh, u16* __restrict__ Irl, u16* __restrict__ Iih, u16* __restrict__ Iil)
{
  size_t i = (size_t)blockIdx.x*256 + threadIdx.x;
  const size_t S = (size_t)BB*DD*DD;
  float2 a = P[i], b = P[i+S], c = P[i+2*S], d = P[i+3*S];
  float rr = a.x+b.x+c.x+d.x, ii = a.y+b.y+c.y+d.y;
  u16 h, l;
  split2(rr, h, l); Irh[i] = h; Irl[i] = l;
  split2(ii, h, l); Iih[i] = h; Iil[i] = l;
}

// ---------- G[n][e] = sum_d eB[n,d]*inner[d,e] ----------
__global__ __launch_bounds__(256) void g_mfma_kernel(
    const u16* __restrict__ Brh, const u16* __restrict__ Brl,
    const u16* __restrict__ Bih, const u16* __restrict__ Bil,
    const u16* __restrict__ Irh, const u16* __restrict__ Irl,
    const u16* __restrict__ Iih, const u16* __restrict__ Iil,
    float2* __restrict__ G)
{
  int b = blockIdx.z;
  int n0 = blockIdx.y*64, e0 = blockIdx.x*64;
  int tid = threadIdx.x, lane = tid & 63, w = tid >> 6;
  int wr = (w >> 1)*32, wc = (w & 1)*32;
  int r16 = lane & 15, g4 = lane >> 4;
  f32x4 p[2][2] = {}, q[2][2] = {}, im[2][2] = {};
  size_t ar_[2], br_[2];
  #pragma unroll
  for (int rg = 0; rg < 2; rg++) {
    ar_[rg] = ((size_t)b*NPTS + (n0 + wr + rg*16 + r16))*DD + g4*8;
    br_[rg] = ((size_t)b*DD + (e0 + wc + rg*16 + r16))*DD + g4*8;
  }
  #pragma unroll
  for (int k0 = 0; k0 < DD; k0 += 32) {
    short8 arh[2], arl[2], aih[2], ail[2], brh[2], brl[2], bih[2], bil[2];
    #pragma unroll
    for (int rg = 0; rg < 2; rg++) {
      arh[rg] = ld8(Brh + ar_[rg] + k0); arl[rg] = ld8(Brl + ar_[rg] + k0);
      aih[rg] = ld8(Bih + ar_[rg] + k0); ail[rg] = ld8(Bil + ar_[rg] + k0);
      brh[rg] = ld8(Irh + br_[rg] + k0); brl[rg] = ld8(Irl + br_[rg] + k0);
      bih[rg] = ld8(Iih + br_[rg] + k0); bil[rg] = ld8(Iil + br_[rg] + k0);
    }
    #pragma unroll
    for (int ra = 0; ra < 2; ra++)
      #pragma unroll
      for (int rb = 0; rb < 2; rb++) {
        p[ra][rb] = MFMA16(arh[ra], brh[rb], p[ra][rb]);
        p[ra][rb] = MFMA16(arh[ra], brl[rb], p[ra][rb]);
        p[ra][rb] = MFMA16(arl[ra], brh[rb], p[ra][rb]);
        q[ra][rb] = MFMA16(aih[ra], bih[rb], q[ra][rb]);
        q[ra][rb] = MFMA16(aih[ra], bil[rb], q[ra][rb]);
        q[ra][rb] = MFMA16(ail[ra], bih[rb], q[ra][rb]);
        im[ra][rb] = MFMA16(arh[ra], bih[rb], im[ra][rb]);
        im[ra][rb] = MFMA16(arh[ra], bil[rb], im[ra][rb]);
        im[ra][rb] = MFMA16(arl[ra], bih[rb], im[ra][rb]);
        im[ra][rb] = MFMA16(aih[ra], brh[rb], im[ra][rb]);
        im[ra][rb] = MFMA16(aih[ra], brl[rb], im[ra][rb]);
        im[ra][rb] = MFMA16(ail[ra], brh[rb], im[ra][rb]);
      }
  }
  #pragma unroll
  for (int ra = 0; ra < 2; ra++)
    #pragma unroll
    for (int rb = 0; rb < 2; rb++)
      #pragma unroll
      for (int j = 0; j < 4; j++) {
        int n = n0 + wr + ra*16 + g4*4 + j;
        int e = e0 + wc + rb*16 + r16;
        G[((size_t)b*NPTS + n)*DD + e] = make_float2(p[ra][rb][j] - q[ra][rb][j], im[ra][rb][j]);
      }
}

// ---------- gnorm + split ----------
__global__ __launch_bounds__(256) void gnormsplit_kernel(const float2* __restrict__ Gf,
    u16* __restrict__ Grh, u16* __restrict__ Grl, u16* __restrict__ Gih, u16* __restrict__ Gil)
{
  size_t row = blockIdx.x;
  const float2* p = Gf + row*DD;
  int tid = threadIdx.x;
  float2 v = p[tid];
  __shared__ float red[256];
  red[tid] = v.x*v.x + v.y*v.y;
  __syncthreads();
  for (int w = 128; w > 0; w >>= 1) { if (tid < w) red[tid] += red[tid+w]; __syncthreads(); }
  float sc = 16.f * rsqrtf(red[0]);
  size_t off = row*DD + tid;
  u16 h, l;
  split2(v.x*sc, h, l); Grh[off] = h; Grl[off] = l;
  split2(v.y*sc, h, l); Gih[off] = h; Gil[off] = l;
}

// ---------- complex linear (pure split-MFMA; plain mapping) ----------
__global__ __launch_bounds__(256) void clinear_mfma_kernel(
    const u16* __restrict__ Arh, const u16* __restrict__ Arl,
    const u16* __restrict__ Aih, const u16* __restrict__ Ail,
    const u16* __restrict__ Wrh, const u16* __restrict__ Wrl,
    const u16* __restrict__ Wih, const u16* __restrict__ Wil,
    const float* __restrict__ br, const float* __restrict__ bi,
    u16* __restrict__ Orh, u16* __restrict__ Orl, u16* __restrict__ Oih, u16* __restrict__ Oil,
    const float* __restrict__ RW, float* __restrict__ GSQ, int mode)
{
  int m0 = blockIdx.y*64, o0 = blockIdx.x*64;
  int tid = threadIdx.x, lane = tid & 63, w = tid >> 6;
  int wr = (w >> 1)*32, wc = (w & 1)*32;
  int r16 = lane & 15, g4 = lane >> 4;
  f32x4 p[2][2] = {}, q[2][2] = {}, im[2][2] = {};
  size_t ar_[2], br_[2];
  #pragma unroll
  for (int rg = 0; rg < 2; rg++) {
    ar_[rg] = (size_t)(m0 + wr + rg*16 + r16)*DD + g4*8;
    br_[rg] = (size_t)(o0 + wc + rg*16 + r16)*DD + g4*8;
  }
  #pragma unroll
  for (int k0 = 0; k0 < DD; k0 += 32) {
    short8 arh[2], arl[2], aih[2], ail[2], brh[2], brl[2], bih[2], bil[2];
    #pragma unroll
    for (int rg = 0; rg < 2; rg++) {
      arh[rg] = ld8(Arh + ar_[rg] + k0); arl[rg] = ld8(Arl + ar_[rg] + k0);
      aih[rg] = ld8(Aih + ar_[rg] + k0); ail[rg] = ld8(Ail + ar_[rg] + k0);
      brh[rg] = ld8(Wrh + br_[rg] + k0); brl[rg] = ld8(Wrl + br_[rg] + k0);
      bih[rg] = ld8(Wih + br_[rg] + k0); bil[rg] = ld8(Wil + br_[rg] + k0);
    }
    #pragma unroll
    for (int ra = 0; ra < 2; ra++)
      #pragma unroll
      for (int rb = 0; rb < 2; rb++) {
        p[ra][rb] = MFMA16(arh[ra], brh[rb], p[ra][rb]);
        p[ra][rb] = MFMA16(arh[ra], brl[rb], p[ra][rb]);
        p[ra][rb] = MFMA16(arl[ra], brh[rb], p[ra][rb]);
        q[ra][rb] = MFMA16(aih[ra], bih[rb], q[ra][rb]);
        q[ra][rb] = MFMA16(aih[ra], bil[rb], q[ra][rb]);
        q[ra][rb] = MFMA16(ail[ra], bih[rb], q[ra][rb]);
        im[ra][rb] = MFMA16(arh[ra], bih[rb], im[ra][rb]);
        im[ra][rb] = MFMA16(arh[ra], bil[rb], im[ra][rb]);
        im[ra][rb] = MFMA16(arl[ra], bih[rb], im[ra][rb]);
        im[ra][rb] = MFMA16(aih[ra], brh[rb], im[ra][rb]);
        im[ra][rb] = MFMA16(aih[ra], brl[rb], im[ra][rb]);
        im[ra][rb] = MFMA16(ail[ra], brh[rb], im[ra][rb]);
      }
  }
  #pragma unroll
  for (int ra = 0; ra < 2; ra++)
    #pragma unroll
    for (int rb = 0; rb < 2; rb++) {
      int o = o0 + wc + rb*16 + r16;
      float brv = br[o], biv = bi[o];
      if (mode == 1) {
        #pragma unroll
        for (int j = 0; j < 4; j++) {
          int m = m0 + wr + ra*16 + g4*4 + j;
          float re = fmaxf(p[ra][rb][j] - q[ra][rb][j] + brv - biv, 0.f);
          float iv = fmaxf(im[ra][rb][j] + brv + biv, 0.f);
          size_t off = (size_t)m*DD + o;
          u16 h, l;
          split2(re, h, l); Orh[off] = h; Orl[off] = l;
          split2(iv, h, l); Oih[off] = h; Oil[off] = l;
        }
      } else {
        int mbase = m0 + wr + ra*16 + g4*4;
        int b = mbase >> 11, nb = mbase & (NPTS-1);
        float rwv = RW[(size_t)b*DD + o];
        float4 gv;
        #pragma unroll
        for (int j = 0; j < 4; j++) {
          float re = p[ra][rb][j] - q[ra][rb][j] + brv - biv;
          float iv = im[ra][rb][j] + brv + biv;
          ((float*)&gv)[j] = (re*re + iv*iv) * rwv;
        }
        *(float4*)(GSQ + ((size_t)b*DD + o)*NPTS + nb) = gv;
      }
    }
}

// ---------- reweight ----------
__global__ void rw_kernel(const float* __restrict__ cls, const float* __restrict__ lbl,
                          float* __restrict__ RW)
{
  int b = blockIdx.x; int d = threadIdx.x;
  float s = 0.f;
  #pragma unroll
  for (int k = 0; k < 16; k++) s += cls[b*16+k] * lbl[k*DD+d];
  RW[b*DD+d] = s;
}

// ---------- sgemm (split MFMA, pre-split W) ----------
__global__ __launch_bounds__(256) void sgemm_kernel(
    const u16* __restrict__ Wh, const u16* __restrict__ Wl,
    const float* __restrict__ X, float* __restrict__ Y,
    const float* __restrict__ RES,
    const float* __restrict__ bias, const float* __restrict__ bng, const float* __restrict__ bnb,
    u16* __restrict__ YBh, u16* __restrict__ YBl, int ybmode,
    int O, int Cin, size_t xbs, size_t ybs, size_t rbs, int flags)
{
  int b = blockIdx.z;
  int n0 = blockIdx.x*64, o0 = blockIdx.y*64;
  const float* x = X + (size_t)b*xbs;
  __shared__ u16 sXh[64][40], sXl[64][40];
  int tid = threadIdx.x, lane = tid & 63, w = tid >> 6;
  int wo = (w >> 1)*32, wn = (w & 1)*32;
  int r16 = lane & 15, g4 = lane >> 4;
  f32x4 acc[2][2] = {};
  int stc = tid >> 3;
  int stn = (tid & 7)*8;
  for (int k0 = 0; k0 < Cin; k0 += 32) {
    const float* px = x + (size_t)(k0+stc)*NPTS + n0 + stn;
    float4 u0 = *(const float4*)px;
    float4 u1 = *(const float4*)(px+4);
    float v[8] = {u0.x,u0.y,u0.z,u0.w,u1.x,u1.y,u1.z,u1.w};
    __syncthreads();
    #pragma unroll
    for (int j = 0; j < 8; j++) {
      u16 h, l; split2(v[j], h, l);
      sXh[stn+j][stc] = h; sXl[stn+j][stc] = l;
    }
    __syncthreads();
    short8 awh[2], awl[2], bxh[2], bxl[2];
    #pragma unroll
    for (int rg = 0; rg < 2; rg++) {
      int orow = o0 + wo + rg*16 + r16;
      if (orow < O) {
        size_t woff = (size_t)orow*Cin + k0 + g4*8;
        awh[rg] = ld8(Wh + woff); awl[rg] = ld8(Wl + woff);
      } else { awh[rg] = zero8(); awl[rg] = zero8(); }
      bxh[rg] = ld8(&sXh[wn + rg*16 + r16][g4*8]);
      bxl[rg] = ld8(&sXl[wn + rg*16 + r16][g4*8]);
    }
    #pragma unroll
    for (int ra = 0; ra < 2; ra++)
      #pragma unroll
      for (int rb = 0; rb < 2; rb++) {
        acc[ra][rb] = MFMA16(awh[ra], bxh[rb], acc[ra][rb]);
        acc[ra][rb] = MFMA16(awh[ra], bxl[rb], acc[ra][rb]);
        acc[ra][rb] = MFMA16(awl[ra], bxh[rb], acc[ra][rb]);
      }
  }
  #pragma unroll
  for (int ra = 0; ra < 2; ra++)
    #pragma unroll
    for (int rb = 0; rb < 2; rb++)
      #pragma unroll
      for (int j = 0; j < 4; j++) {
        int o = o0 + wo + ra*16 + g4*4 + j;
        if (o >= O) continue;
        int n = n0 + wn + rb*16 + r16;
        float v = acc[ra][rb][j];
        if (flags & 1) v += bias[o];
        if (flags & 2) v = v * (bng[o] * rsqrtf(1.f + 1e-5f)) + bnb[o];
        if (flags & 4) v = fmaxf(v, 0.f);
        if (flags & 8) v += RES[(size_t)b*rbs + (size_t)o*NPTS + n];
        if (ybmode == 0) Y[(size_t)b*ybs + (size_t)o*NPTS + n] = v;
        else if (ybmode == 1) YBh[(size_t)b*ybs + (size_t)o*NPTS + n] = f2bf(v);
        else {
          u16 h, l; split2(v, h, l);
          size_t off = ((size_t)b*NPTS + n)*32 + o;
          YBh[off] = h; YBl[off] = l;
        }
      }
}

// ---------- sastat: flash pass 1, m-chunked; XCD-pinned (b in low 3 bits) ----------
__global__ __launch_bounds__(256) void sastat_kernel(
    const u16* __restrict__ Qh, const u16* __restrict__ Ql,
    float* __restrict__ PM, float* __restrict__ PS)
{
  int bx = blockIdx.x;
  int b = bx & 7;
  int t = bx >> 3;
  int ch = t & 3;
  int n0 = (t >> 2)*64;
  size_t base = (size_t)b*NPTS*32;
  int tid = threadIdx.x, lane = tid & 63, wid = tid >> 6;
  int r16 = lane & 15, g4 = lane >> 4;
  size_t ao = base + (size_t)(n0 + wid*16 + r16)*32 + g4*8;
  short8 ah = ld8(Qh + ao), al = ld8(Ql + ao);
  float pm[4] = {-3.4e38f,-3.4e38f,-3.4e38f,-3.4e38f};
  float ps[4] = {0.f,0.f,0.f,0.f};
  int mbeg = ch*512, mend = mbeg + 512;
  for (int mt = mbeg; mt < mend; mt += 32) {
    size_t bo0 = base + (size_t)(mt + r16)*32 + g4*8;
    size_t bo1 = bo0 + 16*32;
    short8 bh0 = ld8(Qh+bo0), bl0 = ld8(Ql+bo0);
    short8 bh1 = ld8(Qh+bo1), bl1 = ld8(Ql+bo1);
    f32x4 a0 = {}, a1 = {};
    a0 = MFMA16(ah, bh0, a0); a0 = MFMA16(ah, bl0, a0); a0 = MFMA16(al, bh0, a0);
    a1 = MFMA16(ah, bh1, a1); a1 = MFMA16(ah, bl1, a1); a1 = MFMA16(al, bh1, a1);
    #pragma unroll
    for (int j = 0; j < 4; j++) {
      float v = fmaxf(a0[j], a1[j]);
      float mn = fmaxf(pm[j], v);
      ps[j] = ps[j]*exp2f((pm[j]-mn)*LOG2E)
            + exp2f((a0[j]-mn)*LOG2E) + exp2f((a1[j]-mn)*LOG2E);
      pm[j] = mn;
    }
  }
  #pragma unroll
  for (int j = 0; j < 4; j++) {
    float m = pm[j], s = ps[j];
    #pragma unroll
    for (int d = 1; d < 16; d <<= 1) {
      float om = __shfl_xor(m, d);
      float os = __shfl_xor(s, d);
      float mn = fmaxf(m, om);
      s = s*exp2f((m-mn)*LOG2E) + os*exp2f((om-mn)*LOG2E);
      m = mn;
    }
    if (r16 == 0) {
      int n_ = n0 + wid*16 + g4*4 + j;
      size_t off = ((size_t)ch*BB + b)*NPTS + n_;
      PM[off] = m; PS[off] = s;
    }
  }
}

// ---------- comb1: mx/rs from 4 chunk partials ----------
__global__ __launch_bounds__(256) void comb1_kernel(
    const float* __restrict__ PM, const float* __restrict__ PS,
    float* __restrict__ MX, float* __restrict__ RS)
{
  size_t i = (size_t)blockIdx.x*256 + threadIdx.x;
  const size_t S = (size_t)BB*NPTS;
  float m0 = PM[i], m1 = PM[i+S], m2 = PM[i+2*S], m3 = PM[i+3*S];
  float mx = fmaxf(fmaxf(m0,m1), fmaxf(m2,m3));
  float den = PS[i]*exp2f((m0-mx)*LOG2E) + PS[i+S]*exp2f((m1-mx)*LOG2E)
            + PS[i+2*S]*exp2f((m2-mx)*LOG2E) + PS[i+3*S]*exp2f((m3-mx)*LOG2E);
  MX[i] = mx; RS[i] = 1.f/den;
}

// ---------- fused flash pass 2 + PV (BM=64, pipelined, XCD-pinned) ----------
// grid = 256 flat: b = bx&7, m0 = (bx>>3)*64. Each XCD owns one batch -> L2-resident Q/xv.
__global__ __launch_bounds__(512) void fused_pv_kernel(
    const u16* __restrict__ Qh, const u16* __restrict__ Ql,
    const float* __restrict__ MX, const float* __restrict__ RS,
    const u16* __restrict__ XV, const float* __restrict__ XRES, size_t res_bs,
    float* __restrict__ OUT)
{
  int bx = blockIdx.x;
  int b = bx & 7;
  int m0 = (bx >> 3)*64;
  size_t qbase = (size_t)b*NPTS*32;
  const u16* xv = XV + (size_t)b*CCH*NPTS;
  const float* mx = MX + (size_t)b*NPTS;
  const float* rs = RS + (size_t)b*NPTS;
  __shared__ u16 Pl[2][64*66];
  __shared__ float csacc[64];
  int tid = threadIdx.x, lane = tid & 63, w = tid >> 6;
  int r16 = lane & 15, g4 = lane >> 4;
  if (tid < 64) csacc[tid] = 0.f;
  int ma = w >> 1, na = w & 1;
  int cw = w*16;
  int swz = (r16 & 7) << 3;
  size_t mo = qbase + (size_t)(m0 + ma*16 + r16)*32 + g4*8;
  short8 mbh = ld8(Qh + mo), mbl = ld8(Ql + mo);
  int wr_base = (ma*16 + r16)*66;
  int nl0 = na*32 + g4*4;
  const u16* pa = xv + (size_t)(cw + r16)*NPTS + g4*8;
  size_t qn_off = qbase + (size_t)(na*32 + r16)*32 + g4*8;
  f32x4 acc[4] = {};
  float csl = 0.f;

  #define COMPUTE_P(NT, QH0, QL0, QH1, QL1, BUF) { \
    f32x4 e0 = {}, e1 = {}; \
    e0 = MFMA16(QH0, mbh, e0); e0 = MFMA16(QH0, mbl, e0); e0 = MFMA16(QL0, mbh, e0); \
    e1 = MFMA16(QH1, mbh, e1); e1 = MFMA16(QH1, mbl, e1); e1 = MFMA16(QL1, mbh, e1); \
    { float4 m4 = *(const float4*)&mx[(NT) + nl0]; \
      float4 r4 = *(const float4*)&rs[(NT) + nl0]; \
      float t0 = exp2f((e0[0]-m4.x)*LOG2E)*r4.x; \
      float t1 = exp2f((e0[1]-m4.y)*LOG2E)*r4.y; \
      float t2 = exp2f((e0[2]-m4.z)*LOG2E)*r4.z; \
      float t3 = exp2f((e0[3]-m4.w)*LOG2E)*r4.w; \
      csl += t0 + t1 + t2 + t3; \
      uint2 pk; \
      pk.x = (unsigned)f2bf(t0) | ((unsigned)f2bf(t1) << 16); \
      pk.y = (unsigned)f2bf(t2) | ((unsigned)f2bf(t3) << 16); \
      *(uint2*)&Pl[BUF][wr_base + (nl0 ^ swz)] = pk; } \
    { float4 m4 = *(const float4*)&mx[(NT) + nl0 + 16]; \
      float4 r4 = *(const float4*)&rs[(NT) + nl0 + 16]; \
      float t0 = exp2f((e1[0]-m4.x)*LOG2E)*r4.x; \
      float t1 = exp2f((e1[1]-m4.y)*LOG2E)*r4.y; \
      float t2 = exp2f((e1[2]-m4.z)*LOG2E)*r4.z; \
      float t3 = exp2f((e1[3]-m4.w)*LOG2E)*r4.w; \
      csl += t0 + t1 + t2 + t3; \
      uint2 pk; \
      pk.x = (unsigned)f2bf(t0) | ((unsigned)f2bf(t1) << 16); \
      pk.y = (unsigned)f2bf(t2) | ((unsigned)f2bf(t3) << 16); \
      *(uint2*)&Pl[BUF][wr_base + ((nl0 + 16) ^ swz)] = pk; } }

  short8 qch[2], qcl[2], qnh[2], qnl[2];
  #pragma unroll
  for (int s = 0; s < 2; s++) {
    size_t o = qn_off + (size_t)(s*16)*32;
    qch[s] = ld8(Qh + o); qcl[s] = ld8(Ql + o);
    o += (size_t)64*32;
    qnh[s] = ld8(Qh + o); qnl[s] = ld8(Ql + o);
  }
  short8 xa0 = ld8(pa), xa1 = ld8(pa + 32);
  short8 xn0 = ld8(pa + 64), xn1 = ld8(pa + 96);
  COMPUTE_P(0, qch[0], qcl[0], qch[1], qcl[1], 0);
  __syncthreads();
  int cur = 0;
  for (int nt = 0; nt < NPTS; nt += 64) {
    short8 q2h[2], q2l[2], x20, x21;
    if (nt + 128 < NPTS) {
      #pragma unroll
      for (int s = 0; s < 2; s++) {
        size_t o = qn_off + (size_t)(nt + 128 + s*16)*32;
        q2h[s] = ld8(Qh + o); q2l[s] = ld8(Ql + o);
      }
      x20 = ld8(pa + nt + 128); x21 = ld8(pa + nt + 160);
    } else { q2h[0]=q2h[1]=q2l[0]=q2l[1]=x20=x21=zero8(); }
    short8 pf0[4], pf1[4];
    #pragma unroll
    for (int mf = 0; mf < 4; mf++) {
      int rowb = (mf*16 + r16)*66;
      pf0[mf] = ld8(&Pl[cur][rowb + ((g4*8) ^ swz)]);
      pf1[mf] = ld8(&Pl[cur][rowb + ((32 + g4*8) ^ swz)]);
    }
    if (nt + 64 < NPTS) { COMPUTE_P(nt + 64, qnh[0], qnl[0], qnh[1], qnl[1], cur ^ 1); }
    #pragma unroll
    for (int mf = 0; mf < 4; mf++) {
      acc[mf] = MFMA16(xa0, pf0[mf], acc[mf]);
      acc[mf] = MFMA16(xa1, pf1[mf], acc[mf]);
    }
    __syncthreads();
    qnh[0]=q2h[0]; qnh[1]=q2h[1]; qnl[0]=q2l[0]; qnl[1]=q2l[1];
    xa0 = xn0; xa1 = xn1; xn0 = x20; xn1 = x21;
    cur ^= 1;
  }
  #undef COMPUTE_P
  {
    float c = csl;
    c += __shfl_xor(c, 16);
    c += __shfl_xor(c, 32);
    if (g4 == 0) atomicAdd(&csacc[ma*16 + r16], c);
  }
  __syncthreads();
  #pragma unroll
  for (int mf = 0; mf < 4; mf++) {
    int m = m0 + mf*16 + r16;
    float ci = 1.f/(1e-9f + csacc[mf*16 + r16]);
    #pragma unroll
    for (int j = 0; j < 4; j++) {
      int c = cw + g4*4 + j;
      float v = XRES[(size_t)b*res_bs + (size_t)c*NPTS + m] - acc[mf][j]*ci;
      OUT[((size_t)b*CCH + c)*NPTS + m] = v;
    }
  }
}

// ---------- log_softmax + transpose ----------
__global__ __launch_bounds__(256) void lsm_kernel(const float* __restrict__ Y,
                                                  float* __restrict__ OUT)
{
  int idx = blockIdx.x*256 + threadIdx.x;
  int b = idx >> 11, n = idx & (NPTS-1);
  const float* p = Y + (size_t)b*NCLASS*NPTS + n;
  float m = -3.4e38f;
  #pragma unroll
  for (int k = 0; k < NCLASS; k++) m = fmaxf(m, p[(size_t)k*NPTS]);
  float s = 0.f;
  #pragma unroll
  for (int k = 0; k < NCLASS; k++) s += expf(p[(size_t)k*NPTS] - m);
  float L = m + logf(s);
  float* o = OUT + (size_t)idx*NCLASS;
  #pragma unroll
  for (int k = 0; k < NCLASS; k++) o[k] = p[(size_t)k*NPTS] - L;
}

extern "C" void kernel_launch(void* const* d_in, const int* in_sizes, int n_in,
                              void* d_out, int out_size, void* d_ws, size_t ws_size,
                              hipStream_t stream)
{
  (void)in_sizes; (void)n_in; (void)out_size; (void)ws_size;
  const float* xyz  = (const float*)d_in[0];
  const float* cls  = (const float*)d_in[1];
  const float* Amat = (const float*)d_in[2];
  const float* Bm   = (const float*)d_in[3];
  const float* W1r  = (const float*)d_in[4];
  const float* b1r  = (const float*)d_in[5];
  const float* W1i  = (const float*)d_in[6];
  const float* b1i  = (const float*)d_in[7];
  const float* W2r  = (const float*)d_in[8];
  const float* b2r  = (const float*)d_in[9];
  const float* W2i  = (const float*)d_in[10];
  const float* b2i  = (const float*)d_in[11];
  const float* lbl  = (const float*)d_in[12];
  const float* ftw1 = (const float*)d_in[13];
  const float* ftg1 = (const float*)d_in[14];
  const float* ftb1 = (const float*)d_in[15];
  const float* ftw2 = (const float*)d_in[16];
  const float* ftg2 = (const float*)d_in[17];
  const float* ftb2 = (const float*)d_in[18];
  const float* saqk = (const float*)d_in[19];
  const float* savw = (const float*)d_in[20];
  const float* savb = (const float*)d_in[21];
  const float* satw = (const float*)d_in[22];
  const float* satb = (const float*)d_in[23];
  const float* sag  = (const float*)d_in[24];
  const float* sab  = (const float*)d_in[25];
  const float* fusew= (const float*)d_in[26];
  const float* fuseg= (const float*)d_in[27];
  const float* fuseb= (const float*)d_in[28];
  const float* c1w  = (const float*)d_in[29];
  const float* c1b  = (const float*)d_in[30];
  const float* bn1g = (const float*)d_in[31];
  const float* bn1b = (const float*)d_in[32];
  const float* c2w  = (const float*)d_in[33];
  const float* c2b  = (const float*)d_in[34];
  float* out = (float*)d_out;

  float* ws = (float*)d_ws;
  const size_t PS  = (size_t)BB*DD*NPTS;
  const size_t ISZ = (size_t)BB*DD*DD;
  u16* U = (u16*)ws;
  u16 *ATrh = U+0*PS, *ATrl = U+1*PS, *ATih = U+2*PS, *ATil = U+3*PS;
  u16 *BTrh = U+4*PS, *BTrl = U+5*PS, *BTih = U+6*PS, *BTil = U+7*PS;
  u16 *Bnrh = U+8*PS, *Bnrl = U+9*PS, *Bnih = U+10*PS, *Bnil = U+11*PS;
  u16 *Irh = U+12*PS, *Irl = U+12*PS+ISZ, *Iih = U+12*PS+2*ISZ, *Iil = U+12*PS+3*ISZ;
  float* gsq = (float*)(U + 12*PS + 4*ISZ);
  float2* PART = (float2*)gsq;
  float2* Gf = (float2*)ws;
  u16 *G1rh = U+4*PS, *G1rl = U+5*PS, *G1ih = U+6*PS, *G1il = U+7*PS;
  u16 *G2rh = U+8*PS, *G2rl = U+9*PS, *G2ih = U+10*PS, *G2il = U+11*PS;
  size_t p = (size_t)BB*NPTS*NPTS;
  float* xfeat = ws + p;  p += (size_t)BB*CCH*NPTS;
  float* feats = ws + p;  p += (size_t)BB*4*CCH*NPTS;
  float* xt1   = ws + p;  p += (size_t)BB*CCH*NPTS;
  float* xt2   = ws + p;  p += (size_t)BB*CCH*NPTS;
  float* ybuf  = ws + p;  p += (size_t)BB*NCLASS*NPTS;
  float* rwb   = ws + p;  p += (size_t)BB*DD;
  float* mxv   = ws + p;  p += (size_t)BB*NPTS;
  float* rsv   = ws + p;  p += (size_t)BB*NPTS;
  float* PMb   = ws + p;  p += (size_t)4*BB*NPTS;
  float* PSb   = ws + p;  p += (size_t)4*BB*NPTS;
  u16* xqh = (u16*)(ws + p);
  u16* xql = xqh + (size_t)BB*NPTS*32;
  u16* xvb = xql + (size_t)BB*NPTS*32;
  u16* wpH = xvb + (size_t)BB*CCH*NPTS;
  u16* wpL = wpH + 557056;

  const int o_w1r=0, o_w1i=65536, o_w2r=131072, o_w2i=196608, o_ft1=262144,
            o_ft2=294912, o_qk=311296, o_vw=327680, o_tw=393216, o_fu=458752,
            o_c1=524288, o_c2=540672;
  WSplit wsp;
  const float* srcs[12] = {W1r,W1i,W2r,W2i,ftw1,ftw2,saqk,savw,satw,fusew,c1w,c2w};
  const int cnts[12] = {65536,65536,65536,65536,32768,16384,16384,65536,65536,65536,16384,6400};
  const int offs[12] = {o_w1r,o_w1i,o_w2r,o_w2i,o_ft1,o_ft2,o_qk,o_vw,o_tw,o_fu,o_c1,o_c2};
  for (int i = 0; i < 12; i++) { wsp.src[i]=srcs[i]; wsp.cnt[i]=cnts[i]; wsp.off[i]=offs[i]; }

  wsplit_kernel<<<dim3(256, 12), 256, 0, stream>>>(wsp, wpH, wpL);
  rw_kernel<<<BB, DD, 0, stream>>>(cls, lbl, rwb);
  ek1_kernel<<<(int)(PS/256), 256, 0, stream>>>(xyz, Amat, Bm,
      ATrh, ATrl, ATih, ATil, BTrh, BTrl, BTih, BTil);
  ek2_kernel<<<(int)(PS/256), 256, 0, stream>>>(xyz, Bm, Bnrh, Bnrl, Bnih, Bnil);
  inner_mfma_kernel<<<dim3(DD/64, DD/64, BB*4), 256, 0, stream>>>(
      ATrh, ATrl, ATih, ATil, BTrh, BTrl, BTih, BTil, PART);
  innred_kernel<<<(int)(ISZ/256), 256, 0, stream>>>(PART, Irh, Irl, Iih, Iil);
  g_mfma_kernel<<<dim3(DD/64, NPTS/64, BB), 256, 0, stream>>>(
      Bnrh, Bnrl, Bnih, Bnil, Irh, Irl, Iih, Iil, Gf);
  gnormsplit_kernel<<<BB*NPTS, 256, 0, stream>>>(Gf, G1rh, G1rl, G1ih, G1il);
  clinear_mfma_kernel<<<dim3(DD/64, (BB*NPTS)/64), 256, 0, stream>>>(
      G1rh, G1rl, G1ih, G1il, wpH+o_w1r, wpL+o_w1r, wpH+o_w1i, wpL+o_w1i,
      b1r, b1i, G2rh, G2rl, G2ih, G2il, nullptr, nullptr, 1);
  clinear_mfma_kernel<<<dim3(DD/64, (BB*NPTS)/64), 256, 0, stream>>>(
      G2rh, G2rl, G2ih, G2il, wpH+o_w2r, wpL+o_w2r, wpH+o_w2i, wpL+o_w2i,
      b2r, b2i, nullptr, nullptr, nullptr, nullptr, rwb, gsq, 2);

  sgemm_kernel<<<dim3(NPTS/64, CCH/64, BB), 256, 0, stream>>>(
      wpH+o_ft1, wpL+o_ft1, gsq, xt1, nullptr, nullptr, ftg1, ftb1, nullptr, nullptr, 0,
      CCH, DD, (size_t)DD*NPTS, (size_t)CCH*NPTS, 0, 2|4);
  sgemm_kernel<<<dim3(NPTS/64, CCH/64, BB), 256, 0, stream>>>(
      wpH+o_ft2, wpL+o_ft2, xt1, xfeat, nullptr, nullptr, ftg2, ftb2, nullptr, nullptr, 0,
      CCH, CCH, (size_t)CCH*NPTS, (size_t)CCH*NPTS, 0, 2);

  const float* xsrc = xfeat;
  size_t xbs = (size_t)CCH*NPTS;
  for (int i = 0; i < 4; i++) {
    sgemm_kernel<<<dim3(NPTS/64, 1, BB), 256, 0, stream>>>(
        wpH+o_qk + i*32*CCH, wpL+o_qk + i*32*CCH, xsrc, nullptr, nullptr,
        nullptr, nullptr, nullptr, xqh, xql, 2, 32, CCH, xbs, 0, 0, 0);
    sastat_kernel<<<1024, 256, 0, stream>>>(xqh, xql, PMb, PSb);
    comb1_kernel<<<(BB*NPTS)/256, 256, 0, stream>>>(PMb, PSb, mxv, rsv);
    sgemm_kernel<<<dim3(NPTS/64, CCH/64, BB), 256, 0, stream>>>(
        wpH+o_vw + i*CCH*CCH, wpL+o_vw + i*CCH*CCH, xsrc, nullptr, nullptr,
        savb + i*CCH, nullptr, nullptr, xvb, nullptr, 1, CCH, CCH, xbs,
        (size_t)CCH*NPTS, 0, 1);
    fused_pv_kernel<<<256, 512, 0, stream>>>(
        xqh, xql, mxv, rsv, xvb, xsrc, xbs, xt2);
    sgemm_kernel<<<dim3(NPTS/64, CCH/64, BB), 256, 0, stream>>>(
        wpH+o_tw + i*CCH*CCH, wpL+o_tw + i*CCH*CCH, xt2, feats + (size_t)i*CCH*NPTS, xsrc,
        satb + i*CCH, sag + i*CCH, sab + i*CCH, nullptr, nullptr, 0,
        CCH, CCH, (size_t)CCH*NPTS, (size_t)4*CCH*NPTS, xbs, 1|2|4|8);
    xsrc = feats + (size_t)i*CCH*NPTS;
    xbs = (size_t)4*CCH*NPTS;
  }

  sgemm_kernel<<<dim3(NPTS/64, CCH/64, BB), 256, 0, stream>>>(
      wpH+o_fu, wpL+o_fu, feats, xt1, nullptr, nullptr, fuseg, fuseb, nullptr, nullptr, 0,
      CCH, 4*CCH, (size_t)4*CCH*NPTS, (size_t)CCH*NPTS, 0, 2|4);
  sgemm_kernel<<<dim3(NPTS/64, CCH/64, BB), 256, 0, stream>>>(
      wpH+o_c1, wpL+o_c1, xt1, xt2, nullptr, c1b, bn1g, bn1b, nullptr, nullptr, 0,
      CCH, CCH, (size_t)CCH*NPTS, (size_t)CCH*NPTS, 0, 1|2|4);
  sgemm_kernel<<<dim3(NPTS/64, 1, BB), 256, 0, stream>>>(
      wpH+o_c2, wpL+o_c2, xt2, ybuf, nullptr, c2b, nullptr, nullptr, nullptr, nullptr, 0,
      NCLASS, CCH, (size_t)CCH*NPTS, (size_t)NCLASS*NPTS, 0, 1);
  lsm_kernel<<<(BB*NPTS)/256, 256, 0, stream>>>(ybuf, out);
}